// Round 14
// baseline (47.656 us; speedup 1.0000x reference)
//
#include <hip/hip_runtime.h>
#include <hip/hip_bf16.h>

#define NPIX 9216
#define CIN 64
#define ICH 32
#define LOG2E 1.4426950408889634f

typedef float f32x4 __attribute__((ext_vector_type(4)));
typedef short bf16x8 __attribute__((ext_vector_type(8)));

#if __has_builtin(__builtin_amdgcn_exp2f)
#define EXP2(x) __builtin_amdgcn_exp2f(x)
#else
#define EXP2(x) exp2f(x)
#endif

// async global->LDS, 16B per lane, dest = wave-uniform base + lane*16
#define GLLDS(gp, lp) \
  __builtin_amdgcn_global_load_lds( \
      (const __attribute__((address_space(1))) unsigned int*)(gp), \
      (__attribute__((address_space(3))) unsigned int*)(lp), 16, 0, 0)

// per-wave counted waits (T4, r13-proven mechanics)
#define VMWAIT4 do { \
  asm volatile("s_waitcnt vmcnt(4)" ::: "memory"); \
  __builtin_amdgcn_sched_barrier(0); } while (0)
#define VMWAIT0 do { \
  asm volatile("s_waitcnt vmcnt(0)" ::: "memory"); \
  __builtin_amdgcn_sched_barrier(0); } while (0)

static __device__ __forceinline__ unsigned short f2bf(float f) {
  union { float f; unsigned u; } v; v.f = f;
  unsigned u = v.u;
  u = u + 0x7FFFu + ((u >> 16) & 1u);
  return (unsigned short)(u >> 16);
}

// ---------------- Kernel A: three 1x1 projections -> bf16 buffers ----------
// (proven r2-r13; zeroes pacc/pl in-kernel)
__global__ __launch_bounds__(256) void proj_kernel(
    const float* __restrict__ x,
    const float* __restrict__ Wt, const float* __restrict__ bt,
    const float* __restrict__ Wp, const float* __restrict__ bp,
    const float* __restrict__ Wg, const float* __restrict__ bg,
    unsigned short* __restrict__ theta,
    unsigned short* __restrict__ phiT,
    unsigned short* __restrict__ vTs,
    float* __restrict__ zbuf)          // pacc+pl region: 304128 floats
{
  const int sub  = blockIdx.x % 36;
  const int grp  = blockIdx.x / 36;      // 0..11, uniform per block
  const int proj = grp >> 2;
  const int og   = (grp & 3) * 8;
  const int m    = sub * 256 + threadIdx.x;

  // zero the partial buffers (76032 float4s over 110592 threads)
  const int t = blockIdx.x * 256 + threadIdx.x;
  if (t < 76032) {
    const f32x4 z4 = {0.f, 0.f, 0.f, 0.f};
    reinterpret_cast<f32x4*>(zbuf)[t] = z4;
  }

  const float* W; const float* bias;
  if (proj == 0)      { W = Wt; bias = bt; }
  else if (proj == 1) { W = Wp; bias = bp; }
  else                { W = Wg; bias = bg; }

  float acc[8];
#pragma unroll
  for (int o = 0; o < 8; ++o) acc[o] = bias[og + o];
  for (int c = 0; c < CIN; ++c) {
    float xv = x[c * NPIX + m];
#pragma unroll
    for (int o = 0; o < 8; ++o) acc[o] = fmaf(W[(og + o) * CIN + c], xv, acc[o]);
  }

  if (proj == 0) {
#pragma unroll
    for (int o = 0; o < 8; ++o) theta[(og + o) * NPIX + m] = f2bf(acc[o] * LOG2E);
  } else if (proj == 1) {
    union { unsigned short s[8]; bf16x8 v; } pk;
#pragma unroll
    for (int o = 0; o < 8; ++o) pk.s[o] = f2bf(acc[o]);
    *reinterpret_cast<bf16x8*>(phiT + m * ICH + og) = pk.v;
  } else {
#pragma unroll
    for (int o = 0; o < 8; ++o) {
      int n = 288 * (og + o) + (m >> 5);       // V row index (reshape identity)
      int k = n & 31;
      int p = ((k >> 2) & 3) * 8 + ((k >> 4) << 2) + (k & 3);  // nu-inverse
      vTs[(m & 31) * NPIX + (n & ~31) + p] = f2bf(acc[o]);
    }
  }
}

// ---------------- Kernel B: flash attention, WAVE-PRIVATE pipeline ---------
// Block = 4 waves on ONE 32-query tile; wave w covers split sg*4+w of 16
// (576 keys = 18 chunks x 32). Each wave stages its own K/V chunks into its
// private 8KB LDS slice (double-buffered 2x4KB) via 4 GLLDS/chunk and paces
// itself with counted vmcnt(4) — NO barriers in the main loop, so waves/CU
// pipeline freely. Fragment values byte-identical to the r12 passing kernel
// (K: verbatim [key][ch] + gp=(l&3)^(k&3) XOR, cancels on read;
//  V: [d][key-slot] 64B rows, naturally 2-way bank-free, no swizzle).
// Epilogue: block LDS reduction (r2 pattern, aliased over dead staging LDS)
// then 1 atomic per value (4 blocks per q-tile).
__global__ __launch_bounds__(256) void attn_kernel(
    const unsigned short* __restrict__ theta,
    const unsigned short* __restrict__ phiT,
    const unsigned short* __restrict__ vTs,
    float* __restrict__ pacc, float* __restrict__ pl)
{
  __shared__ __align__(16) unsigned char lds[4][8192];   // per-wave slice
  __shared__ float lbuf[4][32];

  const int tid = threadIdx.x;
  const int l   = tid & 63;
  const int w   = tid >> 6;          // 0..3
  const int r16 = l & 15;
  const int g   = l >> 4;
  const int qt    = blockIdx.x >> 2;       // 0..287
  const int sg    = blockIdx.x & 3;
  const int split = sg * 4 + w;            // 0..15
  const int qbase = qt * 32;
  const int keybase = split * 576;
  const int cbase = (unsigned)(qt * 5 + sg * 7) % 18;   // de-lockstep

  // two Q fragments (theta pre-scaled by LOG2E)
  bf16x8 qf0 = *reinterpret_cast<const bf16x8*>(theta + (qbase + r16) * ICH + 8 * g);
  bf16x8 qf1 = *reinterpret_cast<const bf16x8*>(theta + (qbase + 16 + r16) * ICH + 8 * g);

  f32x4 acc00 = {0.f, 0.f, 0.f, 0.f}, acc01 = {0.f, 0.f, 0.f, 0.f};
  f32x4 acc10 = {0.f, 0.f, 0.f, 0.f}, acc11 = {0.f, 0.f, 0.f, 0.f};
  const f32x4 z4 = {0.f, 0.f, 0.f, 0.f};
  float l_run0 = 0.f, l_run1 = 0.f;

  unsigned char* Lw = &lds[w][0];
  const int kk = l >> 2;                    // staging helpers
  const int gp = (l & 3) ^ (kk & 3);

  // ---- stage one 32-key chunk (4KB: K 2KB + V 2KB) = 4 GLLDS/wave ----
  auto stage = [&](int buf, int cc) {
    unsigned char* Lb = Lw + buf * 4096;
    const int key0 = keybase + cc * 32;
    GLLDS(phiT + (key0 + kk) * ICH + gp * 8,        Lb);          // K keys 0-15
    GLLDS(phiT + (key0 + 16 + kk) * ICH + gp * 8,   Lb + 1024);   // K keys 16-31
    GLLDS(vTs + kk * NPIX + key0 + (l & 3) * 8,     Lb + 2048);   // V ch 0-15
    GLLDS(vTs + (16 + kk) * NPIX + key0 + (l & 3) * 8, Lb + 3072);// V ch 16-31
  };

  // ---- one 32-key step (fragment math verbatim r12 passing kernel) ----
  auto step = [&](const unsigned char* Lb) {
    const int kx = (g ^ (r16 & 3)) << 4;            // K read swizzle (cancels gp)
    const bf16x8 kf0 = *reinterpret_cast<const bf16x8*>(Lb + r16 * 64 + kx);
    const bf16x8 kf1 = *reinterpret_cast<const bf16x8*>(Lb + 1024 + r16 * 64 + kx);
    const bf16x8 vf0 = *reinterpret_cast<const bf16x8*>(Lb + 2048 + r16 * 64 + g * 16);
    const bf16x8 vf1 = *reinterpret_cast<const bf16x8*>(Lb + 3072 + r16 * 64 + g * 16);

    f32x4 cs00 = __builtin_amdgcn_mfma_f32_16x16x32_bf16(kf0, qf0, z4, 0, 0, 0);
    f32x4 cs01 = __builtin_amdgcn_mfma_f32_16x16x32_bf16(kf1, qf0, z4, 0, 0, 0);
    f32x4 cs10 = __builtin_amdgcn_mfma_f32_16x16x32_bf16(kf0, qf1, z4, 0, 0, 0);
    f32x4 cs11 = __builtin_amdgcn_mfma_f32_16x16x32_bf16(kf1, qf1, z4, 0, 0, 0);

    float p0[8], p1[8]; float ps0 = 0.f, ps1 = 0.f;
#pragma unroll
    for (int j = 0; j < 4; ++j) {
      p0[j]     = EXP2(cs00[j]); ps0 += p0[j];
      p0[4 + j] = EXP2(cs01[j]); ps0 += p0[4 + j];
      p1[j]     = EXP2(cs10[j]); ps1 += p1[j];
      p1[4 + j] = EXP2(cs11[j]); ps1 += p1[4 + j];
    }
    l_run0 += ps0; l_run1 += ps1;

    union { unsigned u[4]; bf16x8 v; } pkA, pkB;
#pragma unroll
    for (int j = 0; j < 4; ++j) {
      asm("v_cvt_pk_bf16_f32 %0, %1, %2" : "=v"(pkA.u[j]) : "v"(p0[2 * j]), "v"(p0[2 * j + 1]));
      asm("v_cvt_pk_bf16_f32 %0, %1, %2" : "=v"(pkB.u[j]) : "v"(p1[2 * j]), "v"(p1[2 * j + 1]));
    }

    acc00 = __builtin_amdgcn_mfma_f32_16x16x32_bf16(pkA.v, vf0, acc00, 0, 0, 0);
    acc01 = __builtin_amdgcn_mfma_f32_16x16x32_bf16(pkA.v, vf1, acc01, 0, 0, 0);
    acc10 = __builtin_amdgcn_mfma_f32_16x16x32_bf16(pkB.v, vf0, acc10, 0, 0, 0);
    acc11 = __builtin_amdgcn_mfma_f32_16x16x32_bf16(pkB.v, vf1, acc11, 0, 0, 0);
  };

  // ---- barrier-free per-wave pipeline ----
  auto chunkid = [&](int c) { int cc = cbase + c; return cc >= 18 ? cc - 18 : cc; };
  stage(0, chunkid(0));
  stage(1, chunkid(1));
#pragma unroll 1
  for (int c = 0; c < 18; ++c) {
    if (c + 1 < 18) { VMWAIT4; } else { VMWAIT0; }   // own chunk-c landed
    step(Lw + (c & 1) * 4096);
    __builtin_amdgcn_sched_barrier(0);               // pin stage after compute
    if (c + 2 < 18) stage(c & 1, chunkid(c + 2));
  }

  // ---- epilogue: block LDS reduction (r2 pattern), then 1 atomic/value ----
  l_run0 += __shfl_xor(l_run0, 16); l_run0 += __shfl_xor(l_run0, 32);
  l_run1 += __shfl_xor(l_run1, 16); l_run1 += __shfl_xor(l_run1, 32);
  if (l < 16) { lbuf[w][l] = l_run0; lbuf[w][16 + l] = l_run1; }

  __syncthreads();                                   // staging LDS now dead
  float* accb = reinterpret_cast<float*>(&lds[0][0]);// [4][64][17] = 17408 B
#pragma unroll
  for (int j = 0; j < 4; ++j) {
    accb[(w * 64 + l) * 17 + j]      = acc00[j];
    accb[(w * 64 + l) * 17 + 4 + j]  = acc01[j];
    accb[(w * 64 + l) * 17 + 8 + j]  = acc10[j];
    accb[(w * 64 + l) * 17 + 12 + j] = acc11[j];
  }
  __syncthreads();

  if (w == 0) {
#pragma unroll
    for (int j = 0; j < 4; ++j) {
      float a00 = 0.f, a01 = 0.f, a10 = 0.f, a11 = 0.f, lst0 = 0.f, lst1 = 0.f;
#pragma unroll
      for (int w2 = 0; w2 < 4; ++w2) {
        a00 += accb[(w2 * 64 + l) * 17 + j];
        a01 += accb[(w2 * 64 + l) * 17 + 4 + j];
        a10 += accb[(w2 * 64 + l) * 17 + 8 + j];
        a11 += accb[(w2 * 64 + l) * 17 + 12 + j];
        lst0 += lbuf[w2][4 * g + j];
        lst1 += lbuf[w2][16 + 4 * g + j];
      }
      const int q0 = qbase + 4 * g + j;
      const int q1 = qbase + 16 + 4 * g + j;
      atomicAdd(&pacc[q0 * ICH + r16],      a00);
      atomicAdd(&pacc[q0 * ICH + 16 + r16], a01);
      atomicAdd(&pacc[q1 * ICH + r16],      a10);
      atomicAdd(&pacc[q1 * ICH + 16 + r16], a11);
      if (r16 == 0) { atomicAdd(&pl[q0], lst0); atomicAdd(&pl[q1], lst1); }
    }
  }
}

// ---------------- Kernel B2: z = pacc/pl, second softmax over 32 ch --------
__global__ __launch_bounds__(256) void merge_kernel(
    const float* __restrict__ pacc, const float* __restrict__ pl,
    float* __restrict__ ybuf)
{
  const int q  = blockIdx.x * 8 + (threadIdx.x >> 5);
  const int ch = threadIdx.x & 31;

  float z  = pacc[q * ICH + ch] / pl[q];
  float zl = z * LOG2E;
  float zm = zl;
#pragma unroll
  for (int k = 1; k < 32; k <<= 1) zm = fmaxf(zm, __shfl_xor(zm, k));
  float e = EXP2(zl - zm);
  float ss = e;
#pragma unroll
  for (int k = 1; k < 32; k <<= 1) ss += __shfl_xor(ss, k);
  ybuf[q * ICH + ch] = e / ss;
}

// ---------------- Kernel C: out = Wo*y + bo + x ----------------------------
// (unchanged, proven r2-r13)
__global__ __launch_bounds__(256) void out_kernel(
    const float* __restrict__ x, const float* __restrict__ Wo,
    const float* __restrict__ bo, const float* __restrict__ ybuf,
    float* __restrict__ out)
{
  const int sub = blockIdx.x % 36;
  const int o0  = (blockIdx.x / 36) * 8;   // uniform per block
  const int s   = sub * 256 + threadIdx.x;

  float acc[8];
#pragma unroll
  for (int o = 0; o < 8; ++o) acc[o] = 0.f;
  for (int c = 0; c < ICH; ++c) {
    float yv = ybuf[c * NPIX + s];   // flat reinterpretation, like reference
#pragma unroll
    for (int o = 0; o < 8; ++o) acc[o] = fmaf(Wo[(o0 + o) * ICH + c], yv, acc[o]);
  }
#pragma unroll
  for (int o = 0; o < 8; ++o) {
    int oc = o0 + o;
    out[oc * NPIX + s] = acc[o] + bo[oc] + x[oc * NPIX + s];
  }
}

extern "C" void kernel_launch(void* const* d_in, const int* in_sizes, int n_in,
                              void* d_out, int out_size, void* d_ws, size_t ws_size,
                              hipStream_t stream) {
  const float* x  = (const float*)d_in[0];
  const float* Wt = (const float*)d_in[1];
  const float* bt = (const float*)d_in[2];
  const float* Wp = (const float*)d_in[3];
  const float* bp = (const float*)d_in[4];
  const float* Wg = (const float*)d_in[5];
  const float* bg = (const float*)d_in[6];
  const float* Wo = (const float*)d_in[7];
  const float* bo = (const float*)d_in[8];
  float* out = (float*)d_out;

  char* ws = (char*)d_ws;
  unsigned short* theta = (unsigned short*)(ws);               // [0, 589824)
  unsigned short* phiT  = (unsigned short*)(ws + 589824);      // [589824, 1179648)
  unsigned short* vTs   = (unsigned short*)(ws + 1179648);     // [1179648, 1769472)
  float* pacc = (float*)(ws + 1769472);                        // [1769472, 2949120)
  float* pl   = (float*)(ws + 2949120);                        // [2949120, 2985984)
  float* ybuf = (float*)(ws);                                  // overlaps theta/phiT (dead after attn)

  proj_kernel<<<432, 256, 0, stream>>>(x, Wt, bt, Wp, bp, Wg, bg, theta, phiT, vTs, pacc);
  attn_kernel<<<1152, 256, 0, stream>>>(theta, phiT, vTs, pacc, pl);
  merge_kernel<<<1152, 256, 0, stream>>>(pacc, pl, ybuf);
  out_kernel<<<288, 256, 0, stream>>>(x, Wo, bo, ybuf, out);
}